// Round 3
// baseline (187.661 us; speedup 1.0000x reference)
//
#include <hip/hip_runtime.h>
#include <math.h>

#define B_  32
#define NS_ 50
#define NQ_ 75
#define T_  128
#define F_  64
#define D_  256
#define K_  5
#define NR_ (NS_ + NQ_)   // 125 z rows per episode (supports then queries)
#define QT_ 25            // query tile per stage-2 block (75 = 3 * 25)

// ---------------------------------------------------------------------------
// Stage 1: fused time-mean pool + projection. One block per (episode, item).
// Slab [T=128, F=64] streamed as float4 (1 KB/wave/iter, 4000 blocks -> HBM
// saturated). Epilogue: thread d holds W[:,d] in 64 VGPRs (loads issued
// before the stream, complete under it), mean broadcast from LDS as float2,
// z[d] = b[d] + sum_f mean[f]*W[f][d] written coalesced (4 MB total).
// ---------------------------------------------------------------------------
__global__ __launch_bounds__(256) void encode_kernel(
    const float* __restrict__ sx, const float* __restrict__ qx,
    const float* __restrict__ Wm, const float* __restrict__ bias,
    float* __restrict__ zbuf)
{
    const int bid = blockIdx.x;            // 0 .. B*NR-1
    const int b = bid / NR_, n = bid % NR_;
    const float* src = (n < NS_)
        ? (sx + (size_t)(b * NS_ + n) * (T_ * F_))
        : (qx + (size_t)(b * NQ_ + (n - NS_)) * (T_ * F_));
    const float4* src4 = (const float4*)src;

    const int tid = threadIdx.x;

    // W column preload (coalesced: consecutive tid -> consecutive addresses)
    float wreg[F_];
#pragma unroll
    for (int f = 0; f < F_; ++f) wreg[f] = Wm[f * D_ + tid];
    const float bd = bias[tid];

    // stream + reduce
    const int f4 = tid & 15;
    float4 acc = make_float4(0.f, 0.f, 0.f, 0.f);
#pragma unroll
    for (int j = 0; j < 8; ++j) {
        int t = (tid >> 4) + j * 16;
        float4 v = src4[t * 16 + f4];
        acc.x += v.x; acc.y += v.y; acc.z += v.z; acc.w += v.w;
    }
    acc.x += __shfl_down(acc.x, 32); acc.y += __shfl_down(acc.y, 32);
    acc.z += __shfl_down(acc.z, 32); acc.w += __shfl_down(acc.w, 32);
    acc.x += __shfl_down(acc.x, 16); acc.y += __shfl_down(acc.y, 16);
    acc.z += __shfl_down(acc.z, 16); acc.w += __shfl_down(acc.w, 16);

    __shared__ float4 red[4][16];
    __shared__ float  mean[F_];
    const int wave = tid >> 6, lane = tid & 63;
    if (lane < 16) red[wave][lane] = acc;
    __syncthreads();
    if (tid < 16) {
        float4 a = red[0][tid], b4 = red[1][tid], c = red[2][tid], d4 = red[3][tid];
        float4 s;
        s.x = (a.x + b4.x + c.x + d4.x) * (1.f / T_);
        s.y = (a.y + b4.y + c.y + d4.y) * (1.f / T_);
        s.z = (a.z + b4.z + c.z + d4.z) * (1.f / T_);
        s.w = (a.w + b4.w + c.w + d4.w) * (1.f / T_);
        ((float4*)mean)[tid] = s;
    }
    __syncthreads();

    // projection epilogue: z[d], d = tid
    float z = bd;
    const float2* m2 = (const float2*)mean;
#pragma unroll
    for (int f2 = 0; f2 < F_ / 2; ++f2) {
        float2 mv = m2[f2];                      // ds_read_b64 broadcast
        z += mv.x * wreg[2 * f2] + mv.y * wreg[2 * f2 + 1];
    }
    zbuf[(size_t)bid * D_ + tid] = z;
}

// ---------------------------------------------------------------------------
// Stage 2: one block per (episode, query-tile of 25). 96 blocks, 256 threads.
// No GEMM left: protomeans in z-space (linearity), then distances.
// ---------------------------------------------------------------------------
__global__ __launch_bounds__(256) void dist_kernel(
    const float* __restrict__ zbuf, const int* __restrict__ sy,
    float* __restrict__ out)
{
    __shared__ float zq[QT_][D_];      // query z rows (25 KB)
    __shared__ float proto[K_][D_];    // prototypes (5 KB)
    __shared__ int   labels[NS_];

    const int tid = threadIdx.x;
    const int bid = blockIdx.x;        // 0 .. B*3-1
    const int b = bid / 3, qt = bid % 3;
    const int q0 = qt * QT_;

    if (tid < NS_) labels[tid] = sy[b * NS_ + tid];
    __syncthreads();

    // prototypes: thread d = tid owns column d across all 5 classes
    {
        float p0 = 0.f, p1 = 0.f, p2 = 0.f, p3 = 0.f, p4 = 0.f;
        int   c0 = 0, c1 = 0, c2 = 0, c3 = 0, c4 = 0;
        for (int s = 0; s < NS_; ++s) {
            float v = zbuf[((size_t)b * NR_ + s) * D_ + tid];   // coalesced, L2-hot
            int l = labels[s];
            if      (l == 0) { p0 += v; ++c0; }
            else if (l == 1) { p1 += v; ++c1; }
            else if (l == 2) { p2 += v; ++c2; }
            else if (l == 3) { p3 += v; ++c3; }
            else             { p4 += v; ++c4; }
        }
        proto[0][tid] = p0 / (float)c0;
        proto[1][tid] = p1 / (float)c1;
        proto[2][tid] = p2 / (float)c2;
        proto[3][tid] = p3 / (float)c3;
        proto[4][tid] = p4 / (float)c4;
    }
    // query z rows for this tile: row j, column tid (coalesced)
#pragma unroll
    for (int j = 0; j < QT_; ++j)
        zq[j][tid] = zbuf[((size_t)b * NR_ + NS_ + q0 + j) * D_ + tid];
    __syncthreads();

    // distances: 125 (q,k) pairs striped over 4 waves
    const int wave = tid >> 6, lane = tid & 63;
    for (int p = wave; p < QT_ * K_; p += 4) {
        const int q = p / K_, k = p % K_;
        float s = 0.f;
#pragma unroll
        for (int j = 0; j < 4; ++j) {
            int d = lane + j * 64;
            float diff = zq[q][d] - proto[k][d];
            s += diff * diff;
        }
        for (int off = 32; off > 0; off >>= 1) s += __shfl_down(s, off);
        if (lane == 0) out[(size_t)(b * NQ_ + q0 + q) * K_ + k] = -sqrtf(s);
    }
}

extern "C" void kernel_launch(void* const* d_in, const int* in_sizes, int n_in,
                              void* d_out, int out_size, void* d_ws, size_t ws_size,
                              hipStream_t stream) {
    const float* sx   = (const float*)d_in[0];   // support_x [32,50,128,64]
    const int*   sy   = (const int*)  d_in[1];   // support_y [32,50]
    const float* qx   = (const float*)d_in[2];   // query_x   [32,75,128,64]
    const float* Wm   = (const float*)d_in[3];   // W [64,256]
    const float* bias = (const float*)d_in[4];   // b [256]
    float* out = (float*)d_out;                  // [2400, 5]
    float* zbuf = (float*)d_ws;                  // B*125*256 floats = 4 MB

    encode_kernel<<<B_ * NR_, 256, 0, stream>>>(sx, qx, Wm, bias, zbuf);
    dist_kernel<<<B_ * 3, 256, 0, stream>>>(zbuf, sy, out);
}

// Round 4
// 173.987 us; speedup vs baseline: 1.0786x; 1.0786x over previous
//
#include <hip/hip_runtime.h>
#include <math.h>

#define B_  32
#define NS_ 50
#define NQ_ 75
#define T_  128
#define F_  64
#define D_  256
#define K_  5
#define NR_ (NS_ + NQ_)   // 125 mean rows per episode (supports then queries)
#define QT_ 5             // query tile per stage-2 block (75 = 15 * 5)
#define NTILE_ 15

typedef float v4f __attribute__((ext_vector_type(4)));

// ---------------------------------------------------------------------------
// Stage 1: time-mean pool, ONE WAVE PER ITEM. No barriers, no LDS, no W.
// Item slab [T=128, F=64] = 2048 float4; lane reads 32 float4 at flat index
// step*64 + lane (each instruction: wave reads 1 KB contiguous). 4 independent
// accumulators -> 32 loads schedulable in flight. Flat idx g = step*64+lane
// gives f4 = lane&15 (t = step*4 + lane>>4), so lanes {l, l+16, l+32, l+48}
// hold partials of the same f4-column: 2 shuffle rounds, lanes 0-15 store.
// Nontemporal loads: 131 MB stream is never reused, skip cache allocation.
// ---------------------------------------------------------------------------
__global__ __launch_bounds__(256) void meanpool_kernel(
    const float* __restrict__ sx, const float* __restrict__ qx,
    float* __restrict__ meanbuf)
{
    const int wave = threadIdx.x >> 6, lane = threadIdx.x & 63;
    const int item = blockIdx.x * 4 + wave;        // 0 .. B*NR-1
    const int b = item / NR_, n = item % NR_;
    const float* src = (n < NS_)
        ? (sx + (size_t)(b * NS_ + n) * (T_ * F_))
        : (qx + (size_t)(b * NQ_ + (n - NS_)) * (T_ * F_));
    const v4f* src4 = (const v4f*)src;

    v4f a0 = 0.f, a1 = 0.f, a2 = 0.f, a3 = 0.f;
#pragma unroll
    for (int s = 0; s < 32; s += 4) {
        v4f v0 = __builtin_nontemporal_load(&src4[(s + 0) * 64 + lane]);
        v4f v1 = __builtin_nontemporal_load(&src4[(s + 1) * 64 + lane]);
        v4f v2 = __builtin_nontemporal_load(&src4[(s + 2) * 64 + lane]);
        v4f v3 = __builtin_nontemporal_load(&src4[(s + 3) * 64 + lane]);
        a0 += v0; a1 += v1; a2 += v2; a3 += v3;
    }
    v4f a = (a0 + a1) + (a2 + a3);

    a.x += __shfl_down(a.x, 32); a.y += __shfl_down(a.y, 32);
    a.z += __shfl_down(a.z, 32); a.w += __shfl_down(a.w, 32);
    a.x += __shfl_down(a.x, 16); a.y += __shfl_down(a.y, 16);
    a.z += __shfl_down(a.z, 16); a.w += __shfl_down(a.w, 16);

    if (lane < 16)
        ((v4f*)meanbuf)[(size_t)item * 16 + lane] = a * (1.f / T_);
}

// ---------------------------------------------------------------------------
// Stage 2: one block per (episode, query-tile of 5). 480 blocks, 256 threads.
//  A) label-grouped protomeans from support means (reads support_y)
//  B) project 10 rows (5 query means + 5 protomeans) through W:
//     thread d caches W[:,d]; rows broadcast from LDS as float2.
//  C) 25 (q,k) pairs over 4 waves: shuffle-reduce Sum((qz-pz)^2) over D=256.
// (Known-good from R2: total dropped 19.8 us with this structure.)
// ---------------------------------------------------------------------------
__global__ __launch_bounds__(256) void proto_kernel(
    const float* __restrict__ meanbuf, const int* __restrict__ sy,
    const float* __restrict__ Wm, const float* __restrict__ bias,
    float* __restrict__ out)
{
    __shared__ float rows[QT_ + K_][F_];   // [0..4] query means, [5..9] protomeans
    __shared__ float zbuf[QT_ + K_][D_];   // projected rows
    __shared__ int   labels[NS_];
    __shared__ float psum[K_][F_];
    __shared__ int   counts[K_];

    const int tid = threadIdx.x;
    const int bid = blockIdx.x;            // 0 .. B*NTILE-1
    const int b = bid / NTILE_, qt = bid % NTILE_;
    const int q0 = qt * QT_;

    if (tid < NS_) labels[tid] = sy[b * NS_ + tid];
    __syncthreads();

    // A) class sums over support means (threads 0..63, f = tid)
    if (tid < F_) {
        const int f = tid;
        float p0 = 0.f, p1 = 0.f, p2 = 0.f, p3 = 0.f, p4 = 0.f;
        for (int s = 0; s < NS_; ++s) {
            float v = meanbuf[((size_t)b * NR_ + s) * F_ + f];
            int l = labels[s];
            if      (l == 0) p0 += v;
            else if (l == 1) p1 += v;
            else if (l == 2) p2 += v;
            else if (l == 3) p3 += v;
            else             p4 += v;
        }
        psum[0][f] = p0; psum[1][f] = p1; psum[2][f] = p2;
        psum[3][f] = p3; psum[4][f] = p4;
    }
    if (tid < K_) {
        int c = 0;
        for (int s = 0; s < NS_; ++s) c += (labels[s] == tid);
        counts[tid] = c;
    }
    for (int i = tid; i < QT_ * F_; i += 256) {
        int r = i / F_, f = i % F_;
        rows[r][f] = meanbuf[((size_t)b * NR_ + NS_ + q0 + r) * F_ + f];
    }
    __syncthreads();
    for (int i = tid; i < K_ * F_; i += 256) {
        int k = i / F_, f = i % F_;
        rows[QT_ + k][f] = psum[k][f] / (float)counts[k];
    }
    __syncthreads();

    // B) projection: thread d = tid owns output column d; float2 LDS reads
    {
        const int d = tid;
        float wreg[F_];
#pragma unroll
        for (int f = 0; f < F_; ++f) wreg[f] = Wm[f * D_ + d];   // coalesced
        const float bd = bias[d];
        for (int r = 0; r < QT_ + K_; ++r) {
            const float2* row2 = (const float2*)rows[r];
            float acc = bd;
#pragma unroll
            for (int f2 = 0; f2 < F_ / 2; ++f2) {
                float2 rv = row2[f2];                            // ds_read_b64 broadcast
                acc += rv.x * wreg[2 * f2] + rv.y * wreg[2 * f2 + 1];
            }
            zbuf[r][d] = acc;
        }
    }
    __syncthreads();

    // C) distances: 25 (q,k) pairs striped over 4 waves
    const int wave = tid >> 6, lane = tid & 63;
    for (int p = wave; p < QT_ * K_; p += 4) {
        const int q = p / K_, k = p % K_;
        float s = 0.f;
#pragma unroll
        for (int j = 0; j < 4; ++j) {
            int d = lane + j * 64;
            float diff = zbuf[q][d] - zbuf[QT_ + k][d];
            s += diff * diff;
        }
        for (int off = 32; off > 0; off >>= 1) s += __shfl_down(s, off);
        if (lane == 0) out[(size_t)(b * NQ_ + q0 + q) * K_ + k] = -sqrtf(s);
    }
}

extern "C" void kernel_launch(void* const* d_in, const int* in_sizes, int n_in,
                              void* d_out, int out_size, void* d_ws, size_t ws_size,
                              hipStream_t stream) {
    const float* sx   = (const float*)d_in[0];   // support_x [32,50,128,64]
    const int*   sy   = (const int*)  d_in[1];   // support_y [32,50]
    const float* qx   = (const float*)d_in[2];   // query_x   [32,75,128,64]
    const float* Wm   = (const float*)d_in[3];   // W [64,256]
    const float* bias = (const float*)d_in[4];   // b [256]
    float* out = (float*)d_out;                  // [2400, 5]
    float* meanbuf = (float*)d_ws;               // B*125*64 floats = 1.0 MB

    meanpool_kernel<<<(B_ * NR_) / 4, 256, 0, stream>>>(sx, qx, meanbuf);
    proto_kernel<<<B_ * NTILE_, 256, 0, stream>>>(meanbuf, sy, Wm, bias, out);
}